// Round 11
// baseline (411.832 us; speedup 1.0000x reference)
//
#include <hip/hip_runtime.h>
#include <math.h>

typedef unsigned short u16;
typedef unsigned int   u32;
typedef __attribute__((ext_vector_type(8))) short bf16x8;
typedef __attribute__((ext_vector_type(4))) float f32x4;
typedef __attribute__((ext_vector_type(4))) u16   u16x4;

// ---------------- problem constants ----------------
#define NB 2
#define NSEQ 4380
#define NPATH 284
#define NHIST 4096
#define DIM 512
#define HEADS 8
#define DHEAD 256
#define INNER 2048
#define N3 6144
#define KSZ 33
#define SCALE_F 0.0625f
#define NBH 16
#define M1 8760   // NB*NSEQ
#define VTHLD 4096
#define VTPLD 288
#define SLD 296    // S LDS pitch (u16): 592B rows, 16B-aligned, 2-way banks

// ---------------- d_out offsets (floats) ----------------
#define OUT0_OFF 0            // (2,4380,2048)
#define OUT1_OFF 17940480     // attn_pathways (2,8,284,284)
#define OUT2_OFF 19230976     // cross_attn_pathways (2,8,284,4096)
#define OUT3_OFF 37843200     // pre-softmax cross_attn_histology (2,8,4096,284)

// ---------------- ws offsets (bytes) ----------------
#define XB_OFF   0u                      // bf16 x           [8760][512]
#define WB_OFF   8970240u                // bf16 w^T         [6144][512]
#define QW_OFF   15261696u               // bf16 q head-major[16][4380][256]
#define KW_OFF   51142656u               // bf16 k
#define VW_OFF   87023616u               // bf16 v  [bh][n][d]
#define VTH_OFF  122904576u              // bf16 v_h^T [16][256][4096]
#define VTP_OFF  156459008u              // bf16 v_p^T [16][256][288] (padded)
#define P2_OFF   0u                      // bf16 P2 [4544][4096]  (aliases dead xb/wb)
#define PP_OFF   158818304u              // f32 [4][16][384][256] split-K partials

__device__ __forceinline__ u16 f2b(float f) {
    u32 u = __float_as_uint(f);
    u += 0x7fffu + ((u >> 16) & 1u);
    return (u16)(u >> 16);
}
__device__ __forceinline__ float b2f(u16 u) {
    return __uint_as_float(((u32)u) << 16);
}

__device__ __forceinline__ void async_cp16(const u16* g, u16* l) {
    __builtin_amdgcn_global_load_lds(
        (const __attribute__((address_space(1))) void*)g,
        (__attribute__((address_space(3))) void*)l,
        16, 0, 0);
}

// Stage a 128x32 bf16 tile [row][k] from row-major g (ld elems, 16B-aligned rows)
__device__ __forceinline__ void stage128x32(const u16* __restrict__ g, int ld,
                                            int row0, int rowmax, int k0,
                                            u16* lds)
{
    const int t = threadIdx.x;          // 0..255
    const int w = t >> 6;
    #pragma unroll
    for (int j = 0; j < 2; ++j) {
        int c = j * 256 + t;            // chunk 0..511
        int r = c >> 2, kg = c & 3;
        int row = row0 + r; if (row > rowmax) row = rowmax;
        const u16* gp = g + (size_t)row * ld + k0 + kg * 8;
        async_cp16(gp, lds + (size_t)(j * 256 + w * 64) * 8);
    }
}

// 128x128 block, 4 waves (2x2 of 64x64), one BK=32 step
__device__ __forceinline__ void compute_step(const u16* shA, const u16* shB,
                                             int wm, int wn, int lane,
                                             f32x4 acc[4][4])
{
    const int lr = lane & 15, lk = (lane >> 4) * 8;
    bf16x8 a[4], b[4];
    #pragma unroll
    for (int i = 0; i < 4; ++i)
        a[i] = *(const bf16x8*)(shA + (size_t)(wm * 64 + i * 16 + lr) * 32 + lk);
    #pragma unroll
    for (int j = 0; j < 4; ++j)
        b[j] = *(const bf16x8*)(shB + (size_t)(wn * 64 + j * 16 + lr) * 32 + lk);
    #pragma unroll
    for (int i = 0; i < 4; ++i)
        #pragma unroll
        for (int j = 0; j < 4; ++j)
            acc[i][j] = __builtin_amdgcn_mfma_f32_16x16x32_bf16(a[i], b[j], acc[i][j], 0, 0, 0);
}

// =====================================================================
// converts
// =====================================================================
__global__ void k_cvt(const float* __restrict__ src, u16* __restrict__ dst, int n4)
{
    int i = blockIdx.x * 256 + threadIdx.x;
    if (i >= n4) return;
    f32x4 f = *(const f32x4*)(src + (size_t)i * 4);
    u16x4 o;
    #pragma unroll
    for (int k = 0; k < 4; ++k) o[k] = f2b(f[k]);
    *(u16x4*)(dst + (size_t)i * 4) = o;
}

__global__ void k_cvt_wT(const float* __restrict__ w, u16* __restrict__ wb)
{
    __shared__ float tile[32][33];
    const int n0 = blockIdx.x * 32, k0 = blockIdx.y * 32;
    const int tx = threadIdx.x & 31, ty = threadIdx.x >> 5;
    #pragma unroll
    for (int r = 0; r < 32; r += 8)
        tile[ty + r][tx] = w[(size_t)(k0 + ty + r) * N3 + n0 + tx];
    __syncthreads();
    #pragma unroll
    for (int r = 0; r < 32; r += 8)
        wb[(size_t)(n0 + ty + r) * DIM + k0 + tx] = f2b(tile[tx][ty + r]);
}

// =====================================================================
// qkv GEMM: xb[8760][512] @ wb^T -> scatter q/k/v (bf16)
// =====================================================================
__global__ void k_qkv(const u16* __restrict__ xb, const u16* __restrict__ wb,
                      u16* __restrict__ qws, u16* __restrict__ kws,
                      u16* __restrict__ vws)
{
    __shared__ u16 sh[2][2][4096];
    const int t = threadIdx.x, lane = t & 63, w = t >> 6;
    const int wm = w >> 1, wn = w & 1;
    const int m0 = blockIdx.y * 128, n0 = blockIdx.x * 128;
    f32x4 acc[4][4] = {};

    stage128x32(xb, DIM, m0, M1 - 1, 0, sh[0][0]);
    stage128x32(wb, DIM, n0, N3 - 1, 0, sh[0][1]);
    const int nt = DIM / 32;   // 16
    for (int kt = 0; kt < nt; ++kt) {
        int cur = kt & 1;
        __syncthreads();
        if (kt + 1 < nt) {
            stage128x32(xb, DIM, m0, M1 - 1, (kt + 1) * 32, sh[cur ^ 1][0]);
            stage128x32(wb, DIM, n0, N3 - 1, (kt + 1) * 32, sh[cur ^ 1][1]);
        }
        compute_step(sh[cur][0], sh[cur][1], wm, wn, lane, acc);
    }

    const int lr = lane & 15, lq = lane >> 4;
    #pragma unroll
    for (int i = 0; i < 4; ++i) {
        #pragma unroll
        for (int j = 0; j < 4; ++j) {
            #pragma unroll
            for (int q = 0; q < 4; ++q) {
                int m = m0 + wm * 64 + i * 16 + lq * 4 + q;
                if (m >= M1) continue;
                int col = n0 + wn * 64 + j * 16 + lr;
                int b = m / NSEQ, n = m - b * NSEQ;
                int part = col >> 11, within = col & 2047;
                int h = within >> 8, d = within & 255;
                int bh = b * HEADS + h;
                float val = acc[i][j][q];
                size_t idx = ((size_t)bh * NSEQ + n) * DHEAD + d;
                if (part == 0)      qws[idx] = f2b(val * SCALE_F);
                else if (part == 1) kws[idx] = f2b(val);
                else                vws[idx] = f2b(val);
            }
        }
    }
}

// =====================================================================
// transpose v: vws[bh][n][d] -> vtp (n<284, padded) and vth (n>=284)
// =====================================================================
__global__ void k_vT(const u16* __restrict__ vws, u16* __restrict__ vtp,
                     u16* __restrict__ vth)
{
    __shared__ u16 tile[64][72];
    const int bh = blockIdx.z;
    const int n0 = blockIdx.x * 64, d0 = blockIdx.y * 64;
    const int t = threadIdx.x;

    #pragma unroll
    for (int i = 0; i < 16; ++i) {
        int lin = i * 256 + t;
        int r = lin >> 6, c = lin & 63;
        int n = n0 + r;
        tile[r][c] = (n < NSEQ) ? vws[((size_t)bh * NSEQ + n) * DHEAD + d0 + c] : (u16)0;
    }
    __syncthreads();

    #pragma unroll
    for (int i = 0; i < 16; ++i) {
        int lin = i * 256 + t;
        int r2 = lin >> 6, c2 = lin & 63;
        int n = n0 + c2, d = d0 + r2;
        u16 v = tile[c2][r2];
        if (n < NPATH) {
            vtp[((size_t)bh * DHEAD + d) * VTPLD + n] = v;
        } else {
            if (n < NPATH + 4)
                vtp[((size_t)bh * DHEAD + d) * VTPLD + n] = 0;
            if (n < NSEQ)
                vth[((size_t)bh * DHEAD + d) * VTHLD + (n - NPATH)] = v;
        }
    }
}

// =====================================================================
// path scores only: q_p @ k_p^T -> out1  (284x284 per bh)
// =====================================================================
__global__ void k_scores_path(const u16* __restrict__ qws, const u16* __restrict__ kws,
                              float* __restrict__ out1)
{
    __shared__ u16 sh[2][2][4096];
    const int t = threadIdx.x, lane = t & 63, w = t >> 6;
    const int wm = w >> 1, wn = w & 1;
    const int bh = blockIdx.z;
    const int i0 = blockIdx.y * 128, j0 = blockIdx.x * 128;
    const u16* A = qws + (size_t)bh * NSEQ * DHEAD;
    const u16* B = kws + (size_t)bh * NSEQ * DHEAD;
    f32x4 acc[4][4] = {};

    stage128x32(A, DHEAD, i0, NPATH - 1, 0, sh[0][0]);
    stage128x32(B, DHEAD, j0, NPATH - 1, 0, sh[0][1]);
    const int nt = DHEAD / 32;  // 8
    for (int kt = 0; kt < nt; ++kt) {
        int cur = kt & 1;
        __syncthreads();
        if (kt + 1 < nt) {
            stage128x32(A, DHEAD, i0, NPATH - 1, (kt + 1) * 32, sh[cur ^ 1][0]);
            stage128x32(B, DHEAD, j0, NPATH - 1, (kt + 1) * 32, sh[cur ^ 1][1]);
        }
        compute_step(sh[cur][0], sh[cur][1], wm, wn, lane, acc);
    }

    const int lr = lane & 15, lq = lane >> 4;
    #pragma unroll
    for (int i = 0; i < 4; ++i) {
        #pragma unroll
        for (int j = 0; j < 4; ++j) {
            #pragma unroll
            for (int q = 0; q < 4; ++q) {
                int ig = i0 + wm * 64 + i * 16 + lq * 4 + q;
                int jg = j0 + wn * 64 + j * 16 + lr;
                if (ig >= NPATH || jg >= NPATH) continue;
                out1[((size_t)bh * NPATH + ig) * NPATH + jg] = acc[i][j][q];
            }
        }
    }
}

// =====================================================================
// fused hist: S = q_h @ k_p^T -> out3 (fp32) + S bf16 in LDS;
// softmax in LDS; out0 rows 284.. = P @ v_p (A from LDS, B = vtp staged)
// =====================================================================
__global__ void k_fh(const u16* __restrict__ qws, const u16* __restrict__ kws,
                     const u16* __restrict__ vtp, float* __restrict__ out3,
                     float* __restrict__ out0)
{
    __shared__ u16 sh[2][2][4096];     // 32 KB staging
    __shared__ u16 S[128 * SLD];       // 74 KB bf16 S/P tile
    __shared__ float invrow[128];
    const int t = threadIdx.x, lane = t & 63, w = t >> 6;
    const int wm = w >> 1, wn = w & 1;
    const int i0 = blockIdx.x * 128;               // hist row tile (0..31)
    const int bh = blockIdx.y, b = bh >> 3, h = bh & 7;
    const u16* A  = qws + ((size_t)bh * NSEQ + NPATH) * DHEAD;   // q_h rows 0..4095
    const u16* Bk = kws + (size_t)bh * NSEQ * DHEAD;             // k_p rows 0..283
    const int lr = lane & 15, lq = lane >> 4;

    // ---- phase 1: S (3 j-passes of 128 cols) ----
    for (int jp = 0; jp < 3; ++jp) {
        f32x4 acc[4][4] = {};
        stage128x32(A, DHEAD, i0, NHIST - 1, 0, sh[0][0]);
        stage128x32(Bk, DHEAD, jp * 128, NPATH - 1, 0, sh[0][1]);
        for (int kt = 0; kt < 8; ++kt) {
            int cur = kt & 1;
            __syncthreads();
            if (kt + 1 < 8) {
                stage128x32(A, DHEAD, i0, NHIST - 1, (kt + 1) * 32, sh[cur ^ 1][0]);
                stage128x32(Bk, DHEAD, jp * 128, NPATH - 1, (kt + 1) * 32, sh[cur ^ 1][1]);
            }
            compute_step(sh[cur][0], sh[cur][1], wm, wn, lane, acc);
        }
        #pragma unroll
        for (int i = 0; i < 4; ++i) {
            #pragma unroll
            for (int j = 0; j < 4; ++j) {
                #pragma unroll
                for (int q = 0; q < 4; ++q) {
                    int r = wm * 64 + i * 16 + lq * 4 + q;
                    int c = jp * 128 + wn * 64 + j * 16 + lr;
                    float v = acc[i][j][q];
                    if (c < NPATH)
                        out3[((size_t)bh * NHIST + i0 + r) * NPATH + c] = v;
                    if (c < 288)
                        S[(size_t)r * SLD + c] = (c < NPATH) ? f2b(v) : (u16)0;
                }
            }
        }
    }
    __syncthreads();

    // ---- softmax: 2 threads per row; halves [0,144) / [144,284) ----
    {
        const int row = t >> 1, half = t & 1;
        u16* srow = S + (size_t)row * SLD + half * 144;
        const int ng = half ? 35 : 36;             // 35*4=140 -> cols 144..283
        float m = -1e30f;
        for (int g = 0; g < ng; ++g) {
            u16x4 vv = *(const u16x4*)(srow + g * 4);
            m = fmaxf(m, fmaxf(fmaxf(b2f(vv[0]), b2f(vv[1])),
                               fmaxf(b2f(vv[2]), b2f(vv[3]))));
        }
        m = fmaxf(m, __shfl_xor(m, 1));
        float s = 0.f;
        for (int g = 0; g < ng; ++g) {
            u16x4 vv = *(const u16x4*)(srow + g * 4);
            u16x4 ov;
            #pragma unroll
            for (int e = 0; e < 4; ++e) {
                float ee = __expf(b2f(vv[e]) - m);
                s += ee;
                ov[e] = f2b(ee);
            }
            *(u16x4*)(srow + g * 4) = ov;
        }
        s += __shfl_xor(s, 1);
        if (half == 0) invrow[row] = 1.f / s;
    }
    __syncthreads();

    // ---- phase 2: out = (P@V) * inv, two d-halves ----
    const u16* Bv = vtp + (size_t)bh * DHEAD * VTPLD;
    for (int dh = 0; dh < 2; ++dh) {
        const int d0 = dh * 128;
        f32x4 acc[4][4] = {};
        __syncthreads();                            // guard sh reuse across halves
        stage128x32(Bv, VTPLD, d0, DHEAD - 1, 0, sh[0][1]);
        for (int kt = 0; kt < 9; ++kt) {            // K = 288
            int cur = kt & 1;
            __syncthreads();
            if (kt + 1 < 9)
                stage128x32(Bv, VTPLD, d0, DHEAD - 1, (kt + 1) * 32, sh[cur ^ 1][1]);
            const int lk = (lane >> 4) * 8;
            bf16x8 a[4], bb[4];
            #pragma unroll
            for (int i = 0; i < 4; ++i)
                a[i] = *(const bf16x8*)(S + (size_t)(wm * 64 + i * 16 + lr) * SLD + kt * 32 + lk);
            #pragma unroll
            for (int j = 0; j < 4; ++j)
                bb[j] = *(const bf16x8*)(sh[cur][1] + (size_t)(wn * 64 + j * 16 + lr) * 32 + lk);
            #pragma unroll
            for (int i = 0; i < 4; ++i)
                #pragma unroll
                for (int j = 0; j < 4; ++j)
                    acc[i][j] = __builtin_amdgcn_mfma_f32_16x16x32_bf16(a[i], bb[j], acc[i][j], 0, 0, 0);
        }
        #pragma unroll
        for (int i = 0; i < 4; ++i) {
            #pragma unroll
            for (int j = 0; j < 4; ++j) {
                #pragma unroll
                for (int q = 0; q < 4; ++q) {
                    int r = wm * 64 + i * 16 + lq * 4 + q;
                    int d = d0 + wn * 64 + j * 16 + lr;
                    out0[((size_t)(b * NSEQ + NPATH + i0 + r)) * INNER + h * DHEAD + d]
                        = acc[i][j][q] * invrow[r];
                }
            }
        }
    }
}

// =====================================================================
// scores vs k_h: q_p @ k_h^T -> out2
// =====================================================================
__global__ void k_scores_kh(const u16* __restrict__ qws, const u16* __restrict__ kws,
                            float* __restrict__ out2)
{
    __shared__ u16 sh[2][2][4096];
    const int t = threadIdx.x, lane = t & 63, w = t >> 6;
    const int wm = w >> 1, wn = w & 1;
    const int bh = blockIdx.z;
    const int i0 = blockIdx.y * 128, j0 = blockIdx.x * 128;
    const u16* A = qws + (size_t)bh * NSEQ * DHEAD;
    const u16* B = kws + ((size_t)bh * NSEQ + NPATH) * DHEAD;
    f32x4 acc[4][4] = {};

    stage128x32(A, DHEAD, i0, NSEQ - 1, 0, sh[0][0]);
    stage128x32(B, DHEAD, j0, NHIST - 1, 0, sh[0][1]);
    const int nt = DHEAD / 32;
    for (int kt = 0; kt < nt; ++kt) {
        int cur = kt & 1;
        __syncthreads();
        if (kt + 1 < nt) {
            stage128x32(A, DHEAD, i0, NSEQ - 1, (kt + 1) * 32, sh[cur ^ 1][0]);
            stage128x32(B, DHEAD, j0, NHIST - 1, (kt + 1) * 32, sh[cur ^ 1][1]);
        }
        compute_step(sh[cur][0], sh[cur][1], wm, wn, lane, acc);
    }

    const int lr = lane & 15, lq = lane >> 4;
    #pragma unroll
    for (int i = 0; i < 4; ++i) {
        #pragma unroll
        for (int j = 0; j < 4; ++j) {
            #pragma unroll
            for (int q = 0; q < 4; ++q) {
                int ig = i0 + wm * 64 + i * 16 + lq * 4 + q;
                if (ig >= NPATH) continue;
                int jg = j0 + wn * 64 + j * 16 + lr;
                out2[((size_t)bh * NPATH + ig) * NHIST + jg] = acc[i][j][q];
            }
        }
    }
}

// =====================================================================
// softmax path-side: single global read, row in LDS
// =====================================================================
__global__ void k_sm2(const float* __restrict__ sc, u16* __restrict__ p2)
{
    __shared__ float buf[NHIST];
    __shared__ float red[4];
    __shared__ float bc[2];
    const int row = blockIdx.x;
    const int tid = threadIdx.x;
    const float* p = sc + (size_t)row * NHIST;

    #pragma unroll
    for (int k = 0; k < 4; ++k) {
        int j4 = tid + k * 256;
        ((f32x4*)buf)[j4] = ((const f32x4*)p)[j4];
    }
    __syncthreads();

    float m = -1e30f;
    #pragma unroll
    for (int k = 0; k < 16; ++k) m = fmaxf(m, buf[tid + k * 256]);
    #pragma unroll
    for (int o = 32; o >= 1; o >>= 1) m = fmaxf(m, __shfl_xor(m, o));
    if ((tid & 63) == 0) red[tid >> 6] = m;
    __syncthreads();
    m = fmaxf(fmaxf(red[0], red[1]), fmaxf(red[2], red[3]));

    float s = 0.f;
    #pragma unroll
    for (int k = 0; k < 16; ++k) {
        int j = tid + k * 256;
        float e = __expf(buf[j] - m);
        buf[j] = e;
        s += e;
    }
    #pragma unroll
    for (int o = 32; o >= 1; o >>= 1) s += __shfl_xor(s, o);
    __syncthreads();
    if ((tid & 63) == 0) red[tid >> 6] = s;
    __syncthreads();
    if (tid == 0) bc[0] = 1.f / (red[0] + red[1] + red[2] + red[3]);
    __syncthreads();
    const float inv = bc[0];

    u16* pr = p2 + (size_t)row * NHIST;
    #pragma unroll
    for (int k = 0; k < 4; ++k) {
        int j4 = tid + k * 256;
        f32x4 f = ((const f32x4*)buf)[j4];
        u16x4 o;
        #pragma unroll
        for (int e = 0; e < 4; ++e) o[e] = f2b(f[e] * inv);
        *(u16x4*)(pr + (size_t)j4 * 4) = o;
    }
}

// =====================================================================
// PV path split-K + reduce
// =====================================================================
__global__ void k_pv_path_split(const u16* __restrict__ p2, const u16* __restrict__ vth,
                                float* __restrict__ pp)
{
    __shared__ u16 sh[2][2][4096];
    const int t = threadIdx.x, lane = t & 63, w = t >> 6;
    const int wm = w >> 1, wn = w & 1;
    const int z = blockIdx.z;            // bh*4 + ks
    const int bh = z >> 2, ks = z & 3;
    const int i0 = blockIdx.y * 128;
    const int d0 = blockIdx.x * 128;
    const int kb = ks * 1024;
    const u16* A = p2 + (size_t)bh * NPATH * NHIST;
    const u16* B = vth + (size_t)bh * DHEAD * VTHLD;
    f32x4 acc[4][4] = {};

    stage128x32(A, NHIST, i0, NPATH - 1, kb, sh[0][0]);
    stage128x32(B, VTHLD, d0, DHEAD - 1, kb, sh[0][1]);
    const int nt = 32;
    for (int kt = 0; kt < nt; ++kt) {
        int cur = kt & 1;
        __syncthreads();
        if (kt + 1 < nt) {
            stage128x32(A, NHIST, i0, NPATH - 1, kb + (kt + 1) * 32, sh[cur ^ 1][0]);
            stage128x32(B, VTHLD, d0, DHEAD - 1, kb + (kt + 1) * 32, sh[cur ^ 1][1]);
        }
        compute_step(sh[cur][0], sh[cur][1], wm, wn, lane, acc);
    }

    float* pb = pp + ((size_t)ks * NBH + bh) * 384 * 256;
    const int lr = lane & 15, lq = lane >> 4;
    #pragma unroll
    for (int i = 0; i < 4; ++i) {
        #pragma unroll
        for (int j = 0; j < 4; ++j) {
            #pragma unroll
            for (int q = 0; q < 4; ++q) {
                int mrow = i0 + wm * 64 + i * 16 + lq * 4 + q;
                int d = d0 + wn * 64 + j * 16 + lr;
                pb[(size_t)mrow * 256 + d] = acc[i][j][q];
            }
        }
    }
}

__global__ void k_pv_reduce(const float* __restrict__ pp, float* __restrict__ out0)
{
    const int i = blockIdx.x;
    const int bh = blockIdx.y;
    const int d = threadIdx.x;
    const int b = bh >> 3, h = bh & 7;
    const size_t kstr = (size_t)NBH * 384 * 256;
    size_t base = ((size_t)bh * 384 + i) * 256 + d;
    float s = pp[base] + pp[base + kstr] + pp[base + 2 * kstr] + pp[base + 3 * kstr];
    out0[((size_t)(b * NSEQ + i)) * INNER + h * DHEAD + d] = s;
}

// =====================================================================
// depthwise conv over seq, accumulate into out0 (all rows)
// =====================================================================
__global__ void k_conv3(const u16* __restrict__ vws, const float* __restrict__ wconv,
                        float* __restrict__ out0)
{
    __shared__ u16 lv[64][DHEAD];
    const int bh = blockIdx.z, b = bh >> 3, h = bh & 7;
    const int n0 = blockIdx.y * 32;
    const int t = threadIdx.x;
    const u16* vb = vws + (size_t)bh * NSEQ * DHEAD;

    #pragma unroll
    for (int i = 0; i < 8; ++i) {
        int oct = i * 256 + t;
        int r = oct >> 5, o = oct & 31;
        int n = n0 - 16 + r;
        bf16x8 v = {};
        if (n >= 0 && n < NSEQ)
            v = *(const bf16x8*)(vb + (size_t)n * DHEAD + o * 8);
        *(bf16x8*)(&lv[r][o * 8]) = v;
    }
    __syncthreads();

    float wc[KSZ];
    #pragma unroll
    for (int tt = 0; tt < KSZ; ++tt) wc[tt] = wconv[h * KSZ + tt];

    const int d = t;
    float win[KSZ];
    #pragma unroll
    for (int j = 0; j < KSZ; ++j) win[j] = b2f(lv[j][d]);

    float* op = out0 + ((size_t)(b * NSEQ + n0)) * INNER + h * DHEAD + d;
    #pragma unroll
    for (int i = 0; i < 32; ++i) {
        if (n0 + i < NSEQ) {
            float acc = 0.f;
            #pragma unroll
            for (int tt = 0; tt < KSZ; ++tt)
                acc += win[(i + tt) % KSZ] * wc[tt];
            op[(size_t)i * INNER] += acc;
        }
        if (i < 31)
            win[i % KSZ] = b2f(lv[i + KSZ][d]);
    }
}

// =====================================================================
extern "C" void kernel_launch(void* const* d_in, const int* in_sizes, int n_in,
                              void* d_out, int out_size, void* d_ws, size_t ws_size,
                              hipStream_t stream)
{
    const float* x     = (const float*)d_in[0];
    const float* wqkv  = (const float*)d_in[1];
    const float* wconv = (const float*)d_in[2];
    float* out = (float*)d_out;
    char*  ws  = (char*)d_ws;

    u16* xb  = (u16*)(ws + XB_OFF);
    u16* wb  = (u16*)(ws + WB_OFF);
    u16* qws = (u16*)(ws + QW_OFF);
    u16* kws = (u16*)(ws + KW_OFF);
    u16* vws = (u16*)(ws + VW_OFF);
    u16* vth = (u16*)(ws + VTH_OFF);
    u16* vtp = (u16*)(ws + VTP_OFF);
    u16* p2  = (u16*)(ws + P2_OFF);
    float* pp = (float*)(ws + PP_OFF);

    float* out0 = out + OUT0_OFF;
    float* out1 = out + OUT1_OFF;
    float* out2 = out + OUT2_OFF;
    float* out3 = out + OUT3_OFF;

    dim3 blk(256);

    // converts
    k_cvt<<<dim3((M1 * DIM / 4 + 255) / 256), blk, 0, stream>>>(x, xb, M1 * DIM / 4);
    k_cvt_wT<<<dim3(N3 / 32, DIM / 32), blk, 0, stream>>>(wqkv, wb);

    // qkv GEMM
    k_qkv<<<dim3(N3 / 128, (M1 + 127) / 128), blk, 0, stream>>>(xb, wb, qws, kws, vws);

    // v transpose
    k_vT<<<dim3((NSEQ + 63) / 64, DHEAD / 64, NBH), blk, 0, stream>>>(vws, vtp, vth);

    // path scores -> out1
    k_scores_path<<<dim3(3, 3, NBH), blk, 0, stream>>>(qws, kws, out1);

    // fused hist: out3 + softmax + PV -> out0 rows 284..
    k_fh<<<dim3(NHIST / 128, NBH), blk, 0, stream>>>(qws, kws, vtp, out3, out0);

    // hist-key scores -> out2
    k_scores_kh<<<dim3(NHIST / 128, 3, NBH), blk, 0, stream>>>(qws, kws, out2);

    // path softmax -> p2
    k_sm2<<<dim3(NBH * NPATH), blk, 0, stream>>>(out2, p2);

    // PV path: split-K=4 partials + reduce -> out0 rows 0..283
    k_pv_path_split<<<dim3(2, 3, NBH * 4), blk, 0, stream>>>(p2, vth, pp);
    k_pv_reduce<<<dim3(NPATH, NBH), blk, 0, stream>>>(pp, out0);

    // conv accumulate (all rows)
    k_conv3<<<dim3(1, (NSEQ + 31) / 32, NBH), blk, 0, stream>>>(vws, wconv, out0);
}

// Round 14
// 357.159 us; speedup vs baseline: 1.1531x; 1.1531x over previous
//
#include <hip/hip_runtime.h>
#include <math.h>

typedef unsigned short u16;
typedef unsigned int   u32;
typedef __attribute__((ext_vector_type(8))) short bf16x8;
typedef __attribute__((ext_vector_type(4))) float f32x4;
typedef __attribute__((ext_vector_type(4))) u16   u16x4;

// ---------------- problem constants ----------------
#define NB 2
#define NSEQ 4380
#define NPATH 284
#define NHIST 4096
#define DIM 512
#define HEADS 8
#define DHEAD 256
#define INNER 2048
#define N3 6144
#define KSZ 33
#define SCALE_F 0.0625f
#define NBH 16
#define M1 8760   // NB*NSEQ
#define VTHLD 4096
#define VTPLD 288
#define P3LD 288

// ---------------- d_out offsets (floats) ----------------
#define OUT0_OFF 0            // (2,4380,2048)
#define OUT1_OFF 17940480     // attn_pathways (2,8,284,284)
#define OUT2_OFF 19230976     // cross_attn_pathways (2,8,284,4096)
#define OUT3_OFF 37843200     // pre-softmax cross_attn_histology (2,8,4096,284)

// ---------------- ws offsets (bytes) ----------------
#define XB_OFF   0u                      // bf16 x           [8760][512]
#define WB_OFF   8970240u                // bf16 w^T         [6144][512]
#define QW_OFF   15261696u               // bf16 q head-major[16][4380][256]
#define KW_OFF   51142656u               // bf16 k
#define VW_OFF   87023616u               // bf16 v  [bh][n][d]
#define VTH_OFF  122904576u              // bf16 v_h^T [16][256][4096]
#define VTP_OFF  156459008u              // bf16 v_p^T [16][256][288] (padded)
#define P2_OFF   0u                      // bf16 P2 [4544][4096]  (aliases dead xb/wb)
#define P3_OFF   37224448u               // bf16 P3 [65536][288]
#define PP_OFF   158818304u              // f32 [4][16][384][256] split-K partials

__device__ __forceinline__ u16 f2b(float f) {
    u32 u = __float_as_uint(f);
    u += 0x7fffu + ((u >> 16) & 1u);
    return (u16)(u >> 16);
}
__device__ __forceinline__ float b2f(u16 u) {
    return __uint_as_float(((u32)u) << 16);
}

__device__ __forceinline__ void async_cp16(const u16* g, u16* l) {
    __builtin_amdgcn_global_load_lds(
        (const __attribute__((address_space(1))) void*)g,
        (__attribute__((address_space(3))) void*)l,
        16, 0, 0);
}

// Stage a 128x32 bf16 tile [row][k] from row-major g (ld elems, 16B-aligned rows)
__device__ __forceinline__ void stage128x32(const u16* __restrict__ g, int ld,
                                            int row0, int rowmax, int k0,
                                            u16* lds)
{
    const int t = threadIdx.x;          // 0..255
    const int w = t >> 6;
    #pragma unroll
    for (int j = 0; j < 2; ++j) {
        int c = j * 256 + t;            // chunk 0..511
        int r = c >> 2, kg = c & 3;
        int row = row0 + r; if (row > rowmax) row = rowmax;
        const u16* gp = g + (size_t)row * ld + k0 + kg * 8;
        async_cp16(gp, lds + (size_t)(j * 256 + w * 64) * 8);
    }
}

// 128x128 block, 4 waves (2x2 of 64x64), one BK=32 step
__device__ __forceinline__ void compute_step(const u16* shA, const u16* shB,
                                             int wm, int wn, int lane,
                                             f32x4 acc[4][4])
{
    const int lr = lane & 15, lk = (lane >> 4) * 8;
    bf16x8 a[4], b[4];
    #pragma unroll
    for (int i = 0; i < 4; ++i)
        a[i] = *(const bf16x8*)(shA + (size_t)(wm * 64 + i * 16 + lr) * 32 + lk);
    #pragma unroll
    for (int j = 0; j < 4; ++j)
        b[j] = *(const bf16x8*)(shB + (size_t)(wn * 64 + j * 16 + lr) * 32 + lk);
    #pragma unroll
    for (int i = 0; i < 4; ++i)
        #pragma unroll
        for (int j = 0; j < 4; ++j)
            acc[i][j] = __builtin_amdgcn_mfma_f32_16x16x32_bf16(a[i], b[j], acc[i][j], 0, 0, 0);
}

// =====================================================================
// converts
// =====================================================================
__global__ void k_cvt(const float* __restrict__ src, u16* __restrict__ dst, int n4)
{
    int i = blockIdx.x * 256 + threadIdx.x;
    if (i >= n4) return;
    f32x4 f = *(const f32x4*)(src + (size_t)i * 4);
    u16x4 o;
    #pragma unroll
    for (int k = 0; k < 4; ++k) o[k] = f2b(f[k]);
    *(u16x4*)(dst + (size_t)i * 4) = o;
}

__global__ void k_cvt_wT(const float* __restrict__ w, u16* __restrict__ wb)
{
    __shared__ float tile[32][33];
    const int n0 = blockIdx.x * 32, k0 = blockIdx.y * 32;
    const int tx = threadIdx.x & 31, ty = threadIdx.x >> 5;   // ty 0..7
    #pragma unroll
    for (int r = 0; r < 32; r += 8)
        tile[ty + r][tx] = w[(size_t)(k0 + ty + r) * N3 + n0 + tx];
    __syncthreads();
    #pragma unroll
    for (int r = 0; r < 32; r += 8)
        wb[(size_t)(n0 + ty + r) * DIM + k0 + tx] = f2b(tile[tx][ty + r]);
}

// =====================================================================
// qkv GEMM: xb[8760][512] @ wb^T -> scatter q/k/v (bf16)
// supertile(8x8) + XCD-chunked swizzle: each XCD walks contiguous
// supertiles whose A+B panel working set (2.1 MB) fits its 4 MB L2.
// grid: 1D 3456 blocks (48 x-tiles * 72 padded y-tiles)
// =====================================================================
__global__ void k_qkv(const u16* __restrict__ xb, const u16* __restrict__ wb,
                      u16* __restrict__ qws, u16* __restrict__ kws,
                      u16* __restrict__ vws)
{
    __shared__ u16 sh[2][2][4096];
    const int bid = blockIdx.x;
    const int wid = (bid & 7) * 432 + (bid >> 3);   // bijective: 8 XCD chunks of 432
    const int su = wid >> 6, within = wid & 63;     // supertile id / 8x8 position
    const int sux = su % 6, suy = su / 6;           // 6 supertiles across x (48/8)
    const int bx = sux * 8 + (within & 7);          // 0..47
    const int by = suy * 8 + (within >> 3);         // 0..71 (padded)
    if (by >= 69) return;
    const int t = threadIdx.x, lane = t & 63, w = t >> 6;
    const int wm = w >> 1, wn = w & 1;
    const int m0 = by * 128, n0 = bx * 128;
    f32x4 acc[4][4] = {};

    stage128x32(xb, DIM, m0, M1 - 1, 0, sh[0][0]);
    stage128x32(wb, DIM, n0, N3 - 1, 0, sh[0][1]);
    const int nt = DIM / 32;   // 16
    for (int kt = 0; kt < nt; ++kt) {
        int cur = kt & 1;
        __syncthreads();
        if (kt + 1 < nt) {
            stage128x32(xb, DIM, m0, M1 - 1, (kt + 1) * 32, sh[cur ^ 1][0]);
            stage128x32(wb, DIM, n0, N3 - 1, (kt + 1) * 32, sh[cur ^ 1][1]);
        }
        compute_step(sh[cur][0], sh[cur][1], wm, wn, lane, acc);
    }

    const int lr = lane & 15, lq = lane >> 4;
    #pragma unroll
    for (int i = 0; i < 4; ++i) {
        #pragma unroll
        for (int j = 0; j < 4; ++j) {
            #pragma unroll
            for (int q = 0; q < 4; ++q) {
                int m = m0 + wm * 64 + i * 16 + lq * 4 + q;
                if (m >= M1) continue;
                int col = n0 + wn * 64 + j * 16 + lr;
                int b = m / NSEQ, n = m - b * NSEQ;
                int part = col >> 11, within2 = col & 2047;
                int h = within2 >> 8, d = within2 & 255;
                int bh = b * HEADS + h;
                float val = acc[i][j][q];
                size_t idx = ((size_t)bh * NSEQ + n) * DHEAD + d;
                if (part == 0)      qws[idx] = f2b(val * SCALE_F);
                else if (part == 1) kws[idx] = f2b(val);
                else                vws[idx] = f2b(val);
            }
        }
    }
}

// =====================================================================
// transpose v: vws[bh][n][d] -> vtp (n<284, padded) and vth (n>=284)
// =====================================================================
__global__ void k_vT(const u16* __restrict__ vws, u16* __restrict__ vtp,
                     u16* __restrict__ vth)
{
    __shared__ u16 tile[64][72];
    const int bh = blockIdx.z;
    const int n0 = blockIdx.x * 64, d0 = blockIdx.y * 64;
    const int t = threadIdx.x;

    #pragma unroll
    for (int i = 0; i < 16; ++i) {
        int lin = i * 256 + t;
        int r = lin >> 6, c = lin & 63;
        int n = n0 + r;
        tile[r][c] = (n < NSEQ) ? vws[((size_t)bh * NSEQ + n) * DHEAD + d0 + c] : (u16)0;
    }
    __syncthreads();

    #pragma unroll
    for (int i = 0; i < 16; ++i) {
        int lin = i * 256 + t;
        int r2 = lin >> 6, c2 = lin & 63;
        int n = n0 + c2, d = d0 + r2;
        u16 v = tile[c2][r2];
        if (n < NPATH) {
            vtp[((size_t)bh * DHEAD + d) * VTPLD + n] = v;
        } else {
            if (n < NPATH + 4)
                vtp[((size_t)bh * DHEAD + d) * VTPLD + n] = 0;
            if (n < NSEQ)
                vth[((size_t)bh * DHEAD + d) * VTHLD + (n - NPATH)] = v;
        }
    }
}

// =====================================================================
// scores vs k_p: q(all) @ k_p^T -> out1 (rows<284) / out3
// =====================================================================
__global__ void k_scores_kp(const u16* __restrict__ qws, const u16* __restrict__ kws,
                            float* __restrict__ out1, float* __restrict__ out3)
{
    __shared__ u16 sh[2][2][4096];
    const int t = threadIdx.x, lane = t & 63, w = t >> 6;
    const int wm = w >> 1, wn = w & 1;
    const int bh = blockIdx.z;
    const int i0 = blockIdx.y * 128, j0 = blockIdx.x * 128;
    const u16* A = qws + (size_t)bh * NSEQ * DHEAD;
    const u16* B = kws + (size_t)bh * NSEQ * DHEAD;
    f32x4 acc[4][4] = {};

    stage128x32(A, DHEAD, i0, NSEQ - 1, 0, sh[0][0]);
    stage128x32(B, DHEAD, j0, NSEQ - 1, 0, sh[0][1]);
    const int nt = DHEAD / 32;  // 8
    for (int kt = 0; kt < nt; ++kt) {
        int cur = kt & 1;
        __syncthreads();
        if (kt + 1 < nt) {
            stage128x32(A, DHEAD, i0, NSEQ - 1, (kt + 1) * 32, sh[cur ^ 1][0]);
            stage128x32(B, DHEAD, j0, NSEQ - 1, (kt + 1) * 32, sh[cur ^ 1][1]);
        }
        compute_step(sh[cur][0], sh[cur][1], wm, wn, lane, acc);
    }

    const int lr = lane & 15, lq = lane >> 4;
    #pragma unroll
    for (int i = 0; i < 4; ++i) {
        #pragma unroll
        for (int j = 0; j < 4; ++j) {
            #pragma unroll
            for (int q = 0; q < 4; ++q) {
                int ig = i0 + wm * 64 + i * 16 + lq * 4 + q;
                int jg = j0 + wn * 64 + j * 16 + lr;
                if (ig >= NSEQ || jg >= NPATH) continue;
                float val = acc[i][j][q];
                if (ig < NPATH)
                    out1[((size_t)bh * NPATH + ig) * NPATH + jg] = val;
                else
                    out3[((size_t)bh * NHIST + (ig - NPATH)) * NPATH + jg] = val;
            }
        }
    }
}

// =====================================================================
// scores vs k_h: q_p @ k_h^T -> out2
// =====================================================================
__global__ void k_scores_kh(const u16* __restrict__ qws, const u16* __restrict__ kws,
                            float* __restrict__ out2)
{
    __shared__ u16 sh[2][2][4096];
    const int t = threadIdx.x, lane = t & 63, w = t >> 6;
    const int wm = w >> 1, wn = w & 1;
    const int bh = blockIdx.z;
    const int i0 = blockIdx.y * 128, j0 = blockIdx.x * 128;
    const u16* A = qws + (size_t)bh * NSEQ * DHEAD;
    const u16* B = kws + ((size_t)bh * NSEQ + NPATH) * DHEAD;
    f32x4 acc[4][4] = {};

    stage128x32(A, DHEAD, i0, NSEQ - 1, 0, sh[0][0]);
    stage128x32(B, DHEAD, j0, NHIST - 1, 0, sh[0][1]);
    const int nt = DHEAD / 32;
    for (int kt = 0; kt < nt; ++kt) {
        int cur = kt & 1;
        __syncthreads();
        if (kt + 1 < nt) {
            stage128x32(A, DHEAD, i0, NSEQ - 1, (kt + 1) * 32, sh[cur ^ 1][0]);
            stage128x32(B, DHEAD, j0, NHIST - 1, (kt + 1) * 32, sh[cur ^ 1][1]);
        }
        compute_step(sh[cur][0], sh[cur][1], wm, wn, lane, acc);
    }

    const int lr = lane & 15, lq = lane >> 4;
    #pragma unroll
    for (int i = 0; i < 4; ++i) {
        #pragma unroll
        for (int j = 0; j < 4; ++j) {
            #pragma unroll
            for (int q = 0; q < 4; ++q) {
                int ig = i0 + wm * 64 + i * 16 + lq * 4 + q;
                if (ig >= NPATH) continue;
                int jg = j0 + wn * 64 + j * 16 + lr;
                out2[((size_t)bh * NPATH + ig) * NHIST + jg] = acc[i][j][q];
            }
        }
    }
}

// =====================================================================
// softmax: single global read; row cached in LDS (sm2) / registers (sm3)
// =====================================================================
__global__ void k_sm2(const float* __restrict__ sc, u16* __restrict__ p2)
{
    __shared__ float buf[NHIST];     // 16 KB
    __shared__ float red[4];
    __shared__ float bc[2];
    const int row = blockIdx.x;
    const int tid = threadIdx.x;
    const float* p = sc + (size_t)row * NHIST;

    #pragma unroll
    for (int k = 0; k < 4; ++k) {
        int j4 = tid + k * 256;
        ((f32x4*)buf)[j4] = ((const f32x4*)p)[j4];
    }
    __syncthreads();

    float m = -1e30f;
    #pragma unroll
    for (int k = 0; k < 16; ++k) m = fmaxf(m, buf[tid + k * 256]);
    #pragma unroll
    for (int o = 32; o >= 1; o >>= 1) m = fmaxf(m, __shfl_xor(m, o));
    if ((tid & 63) == 0) red[tid >> 6] = m;
    __syncthreads();
    m = fmaxf(fmaxf(red[0], red[1]), fmaxf(red[2], red[3]));

    float s = 0.f;
    #pragma unroll
    for (int k = 0; k < 16; ++k) {
        int j = tid + k * 256;
        float e = __expf(buf[j] - m);
        buf[j] = e;
        s += e;
    }
    #pragma unroll
    for (int o = 32; o >= 1; o >>= 1) s += __shfl_xor(s, o);
    __syncthreads();
    if ((tid & 63) == 0) red[tid >> 6] = s;
    __syncthreads();
    if (tid == 0) bc[0] = 1.f / (red[0] + red[1] + red[2] + red[3]);
    __syncthreads();
    const float inv = bc[0];

    u16* pr = p2 + (size_t)row * NHIST;
    #pragma unroll
    for (int k = 0; k < 4; ++k) {
        int j4 = tid + k * 256;
        f32x4 f = ((const f32x4*)buf)[j4];
        u16x4 o;
        #pragma unroll
        for (int e = 0; e < 4; ++e) o[e] = f2b(f[e] * inv);
        *(u16x4*)(pr + (size_t)j4 * 4) = o;
    }
}

__global__ void k_sm3(const float* __restrict__ sc, u16* __restrict__ p3)
{
    const int row  = blockIdx.x * 4 + (threadIdx.x >> 6);
    const int lane = threadIdx.x & 63;
    const float* p = sc + (size_t)row * NPATH;

    float v[5];
    #pragma unroll
    for (int k = 0; k < 5; ++k) {
        int j = lane + k * 64;
        v[k] = (j < NPATH) ? p[j] : -1e30f;
    }

    float m = fmaxf(fmaxf(fmaxf(v[0], v[1]), fmaxf(v[2], v[3])), v[4]);
    #pragma unroll
    for (int o = 32; o >= 1; o >>= 1) m = fmaxf(m, __shfl_xor(m, o));

    float s = 0.f;
    #pragma unroll
    for (int k = 0; k < 5; ++k) {
        float e = __expf(v[k] - m);
        v[k] = e;
        s += e;
    }
    #pragma unroll
    for (int o = 32; o >= 1; o >>= 1) s += __shfl_xor(s, o);
    const float inv = 1.f / s;

    u16* pr = p3 + (size_t)row * P3LD;
    #pragma unroll
    for (int k = 0; k < 5; ++k) {
        int j = lane + k * 64;
        if (j < P3LD)
            pr[j] = (j < NPATH) ? f2b(v[k] * inv) : (u16)0;
    }
}

// =====================================================================
// PV path split-K: partial[ks] = P2[:, ks*1024:(ks+1)*1024] @ v_h[...]
// =====================================================================
__global__ void k_pv_path_split(const u16* __restrict__ p2, const u16* __restrict__ vth,
                                float* __restrict__ pp)
{
    __shared__ u16 sh[2][2][4096];
    const int t = threadIdx.x, lane = t & 63, w = t >> 6;
    const int wm = w >> 1, wn = w & 1;
    const int z = blockIdx.z;            // bh*4 + ks
    const int bh = z >> 2, ks = z & 3;
    const int i0 = blockIdx.y * 128;
    const int d0 = blockIdx.x * 128;
    const int kb = ks * 1024;
    const u16* A = p2 + (size_t)bh * NPATH * NHIST;
    const u16* B = vth + (size_t)bh * DHEAD * VTHLD;
    f32x4 acc[4][4] = {};

    stage128x32(A, NHIST, i0, NPATH - 1, kb, sh[0][0]);
    stage128x32(B, VTHLD, d0, DHEAD - 1, kb, sh[0][1]);
    const int nt = 32;
    for (int kt = 0; kt < nt; ++kt) {
        int cur = kt & 1;
        __syncthreads();
        if (kt + 1 < nt) {
            stage128x32(A, NHIST, i0, NPATH - 1, kb + (kt + 1) * 32, sh[cur ^ 1][0]);
            stage128x32(B, VTHLD, d0, DHEAD - 1, kb + (kt + 1) * 32, sh[cur ^ 1][1]);
        }
        compute_step(sh[cur][0], sh[cur][1], wm, wn, lane, acc);
    }

    float* pb = pp + ((size_t)ks * NBH + bh) * 384 * 256;
    const int lr = lane & 15, lq = lane >> 4;
    #pragma unroll
    for (int i = 0; i < 4; ++i) {
        #pragma unroll
        for (int j = 0; j < 4; ++j) {
            #pragma unroll
            for (int q = 0; q < 4; ++q) {
                int mrow = i0 + wm * 64 + i * 16 + lq * 4 + q;
                int d = d0 + wn * 64 + j * 16 + lr;
                pb[(size_t)mrow * 256 + d] = acc[i][j][q];
            }
        }
    }
}

// reduce 4 partials -> out0 rows 0..283 (fixed order: deterministic)
__global__ void k_pv_reduce(const float* __restrict__ pp, float* __restrict__ out0)
{
    const int i = blockIdx.x;            // 0..283
    const int bh = blockIdx.y;
    const int d = threadIdx.x;
    const int b = bh >> 3, h = bh & 7;
    const size_t kstr = (size_t)NBH * 384 * 256;
    size_t base = ((size_t)bh * 384 + i) * 256 + d;
    float s = pp[base] + pp[base + kstr] + pp[base + 2 * kstr] + pp[base + 3 * kstr];
    out0[((size_t)(b * NSEQ + i)) * INNER + h * DHEAD + d] = s;
}

// =====================================================================
// PV hist: out0 rows 284.. = P3 @ v_p   (K=288 padded)
// =====================================================================
__global__ void k_pv_hist(const u16* __restrict__ p3, const u16* __restrict__ vtp,
                          float* __restrict__ out0)
{
    __shared__ u16 sh[2][2][4096];
    const int t = threadIdx.x, lane = t & 63, w = t >> 6;
    const int wm = w >> 1, wn = w & 1;
    const int bh = blockIdx.z, b = bh >> 3, h = bh & 7;
    const int i0 = blockIdx.y * 128;     // 0..31
    const int d0 = blockIdx.x * 128;     // 0..1
    const u16* A = p3 + (size_t)bh * NHIST * P3LD;
    const u16* B = vtp + (size_t)bh * DHEAD * VTPLD;
    f32x4 acc[4][4] = {};

    stage128x32(A, P3LD, i0, NHIST - 1, 0, sh[0][0]);
    stage128x32(B, VTPLD, d0, DHEAD - 1, 0, sh[0][1]);
    const int nt = P3LD / 32;   // 9
    for (int kt = 0; kt < nt; ++kt) {
        int cur = kt & 1;
        __syncthreads();
        if (kt + 1 < nt) {
            stage128x32(A, P3LD, i0, NHIST - 1, (kt + 1) * 32, sh[cur ^ 1][0]);
            stage128x32(B, VTPLD, d0, DHEAD - 1, (kt + 1) * 32, sh[cur ^ 1][1]);
        }
        compute_step(sh[cur][0], sh[cur][1], wm, wn, lane, acc);
    }

    const int lr = lane & 15, lq = lane >> 4;
    #pragma unroll
    for (int i = 0; i < 4; ++i) {
        #pragma unroll
        for (int j = 0; j < 4; ++j) {
            #pragma unroll
            for (int q = 0; q < 4; ++q) {
                int mrow = i0 + wm * 64 + i * 16 + lq * 4 + q;   // 0..4095
                int d = d0 + wn * 64 + j * 16 + lr;
                out0[((size_t)(b * NSEQ + NPATH + mrow)) * INNER + h * DHEAD + d] = acc[i][j][q];
            }
        }
    }
}

// =====================================================================
// depthwise conv over seq, accumulate into out0
// =====================================================================
__global__ void k_conv3(const u16* __restrict__ vws, const float* __restrict__ wconv,
                        float* __restrict__ out0)
{
    __shared__ u16 lv[64][DHEAD];        // 32 KB bf16
    const int bh = blockIdx.z, b = bh >> 3, h = bh & 7;
    const int n0 = blockIdx.y * 32;
    const int t = threadIdx.x;
    const u16* vb = vws + (size_t)bh * NSEQ * DHEAD;

    #pragma unroll
    for (int i = 0; i < 8; ++i) {
        int oct = i * 256 + t;
        int r = oct >> 5, o = oct & 31;
        int n = n0 - 16 + r;
        bf16x8 v = {};
        if (n >= 0 && n < NSEQ)
            v = *(const bf16x8*)(vb + (size_t)n * DHEAD + o * 8);
        *(bf16x8*)(&lv[r][o * 8]) = v;
    }
    __syncthreads();

    float wc[KSZ];
    #pragma unroll
    for (int tt = 0; tt < KSZ; ++tt) wc[tt] = wconv[h * KSZ + tt];

    const int d = t;
    float win[KSZ];
    #pragma unroll
    for (int j = 0; j < KSZ; ++j) win[j] = b2f(lv[j][d]);

    float* op = out0 + ((size_t)(b * NSEQ + n0)) * INNER + h * DHEAD + d;
    #pragma unroll
    for (int i = 0; i < 32; ++i) {
        if (n0 + i < NSEQ) {
            float acc = 0.f;
            #pragma unroll
            for (int tt = 0; tt < KSZ; ++tt)
                acc += win[(i + tt) % KSZ] * wc[tt];
            op[(size_t)i * INNER] += acc;
        }
        if (i < 31)
            win[i % KSZ] = b2f(lv[i + KSZ][d]);
    }
}

// =====================================================================
extern "C" void kernel_launch(void* const* d_in, const int* in_sizes, int n_in,
                              void* d_out, int out_size, void* d_ws, size_t ws_size,
                              hipStream_t stream)
{
    const float* x     = (const float*)d_in[0];
    const float* wqkv  = (const float*)d_in[1];
    const float* wconv = (const float*)d_in[2];
    float* out = (float*)d_out;
    char*  ws  = (char*)d_ws;

    u16* xb  = (u16*)(ws + XB_OFF);
    u16* wb  = (u16*)(ws + WB_OFF);
    u16* qws = (u16*)(ws + QW_OFF);
    u16* kws = (u16*)(ws + KW_OFF);
    u16* vws = (u16*)(ws + VW_OFF);
    u16* vth = (u16*)(ws + VTH_OFF);
    u16* vtp = (u16*)(ws + VTP_OFF);
    u16* p2  = (u16*)(ws + P2_OFF);
    u16* p3  = (u16*)(ws + P3_OFF);
    float* pp = (float*)(ws + PP_OFF);

    float* out0 = out + OUT0_OFF;
    float* out1 = out + OUT1_OFF;
    float* out2 = out + OUT2_OFF;
    float* out3 = out + OUT3_OFF;

    dim3 blk(256);

    // converts
    k_cvt<<<dim3((M1 * DIM / 4 + 255) / 256), blk, 0, stream>>>(x, xb, M1 * DIM / 4);
    k_cvt_wT<<<dim3(N3 / 32, DIM / 32), blk, 0, stream>>>(wqkv, wb);

    // qkv GEMM (supertile + XCD swizzle; 48 x-tiles * 72 padded y-tiles)
    k_qkv<<<dim3(3456), blk, 0, stream>>>(xb, wb, qws, kws, vws);

    // v transpose
    k_vT<<<dim3((NSEQ + 63) / 64, DHEAD / 64, NBH), blk, 0, stream>>>(vws, vtp, vth);

    // scores
    k_scores_kp<<<dim3(3, (NSEQ + 127) / 128, NBH), blk, 0, stream>>>(qws, kws, out1, out3);
    k_scores_kh<<<dim3(NHIST / 128, 3, NBH), blk, 0, stream>>>(qws, kws, out2);

    // softmax -> bf16 P
    k_sm2<<<dim3(NBH * NPATH), blk, 0, stream>>>(out2, p2);
    k_sm3<<<dim3(NBH * NHIST / 4), blk, 0, stream>>>(out3, p3);

    // PV path: split-K=4 partials + deterministic reduce
    k_pv_path_split<<<dim3(2, 3, NBH * 4), blk, 0, stream>>>(p2, vth, pp);
    k_pv_reduce<<<dim3(NPATH, NBH), blk, 0, stream>>>(pp, out0);

    // PV hist
    k_pv_hist<<<dim3(2, 32, NBH), blk, 0, stream>>>(p3, vtp, out0);

    // conv accumulate
    k_conv3<<<dim3(1, (NSEQ + 31) / 32, NBH), blk, 0, stream>>>(vws, wconv, out0);
}

// Round 15
// 353.327 us; speedup vs baseline: 1.1656x; 1.0108x over previous
//
#include <hip/hip_runtime.h>
#include <math.h>

typedef unsigned short u16;
typedef unsigned int   u32;
typedef __attribute__((ext_vector_type(8))) short bf16x8;
typedef __attribute__((ext_vector_type(4))) float f32x4;
typedef __attribute__((ext_vector_type(4))) u16   u16x4;

// ---------------- problem constants ----------------
#define NB 2
#define NSEQ 4380
#define NPATH 284
#define NHIST 4096
#define DIM 512
#define HEADS 8
#define DHEAD 256
#define INNER 2048
#define N3 6144
#define KSZ 33
#define SCALE_F 0.0625f
#define NBH 16
#define M1 8760   // NB*NSEQ
#define VTHLD 4096
#define VTPLD 288
#define P3LD 288

// ---------------- d_out offsets (floats) ----------------
#define OUT0_OFF 0            // (2,4380,2048)
#define OUT1_OFF 17940480     // attn_pathways (2,8,284,284)
#define OUT2_OFF 19230976     // cross_attn_pathways (2,8,284,4096)
#define OUT3_OFF 37843200     // pre-softmax cross_attn_histology (2,8,4096,284)

// ---------------- ws offsets (bytes) ----------------
#define XB_OFF   0u                      // bf16 x           [8760][512]
#define WB_OFF   8970240u                // bf16 w^T         [6144][512]
#define QW_OFF   15261696u               // bf16 q head-major[16][4380][256]
#define KW_OFF   51142656u               // bf16 k
#define VW_OFF   87023616u               // bf16 v  [bh][n][d]
#define VTH_OFF  122904576u              // bf16 v_h^T [16][256][4096]
#define VTP_OFF  156459008u              // bf16 v_p^T [16][256][288] (padded)
#define P2_OFF   0u                      // bf16 P2 [4544][4096]  (aliases dead xb/wb)
#define P3_OFF   37224448u               // bf16 P3 [65536][288]
#define PP_OFF   158818304u              // f32 [4][16][384][256] split-K partials

__device__ __forceinline__ u16 f2b(float f) {
    u32 u = __float_as_uint(f);
    u += 0x7fffu + ((u >> 16) & 1u);
    return (u16)(u >> 16);
}
__device__ __forceinline__ float b2f(u16 u) {
    return __uint_as_float(((u32)u) << 16);
}

__device__ __forceinline__ void async_cp16(const u16* g, u16* l) {
    __builtin_amdgcn_global_load_lds(
        (const __attribute__((address_space(1))) void*)g,
        (__attribute__((address_space(3))) void*)l,
        16, 0, 0);
}

// Stage a 128x32 bf16 tile [row][k] from row-major g (ld elems, 16B-aligned rows)
__device__ __forceinline__ void stage128x32(const u16* __restrict__ g, int ld,
                                            int row0, int rowmax, int k0,
                                            u16* lds)
{
    const int t = threadIdx.x;          // 0..255
    const int w = t >> 6;
    #pragma unroll
    for (int j = 0; j < 2; ++j) {
        int c = j * 256 + t;            // chunk 0..511
        int r = c >> 2, kg = c & 3;
        int row = row0 + r; if (row > rowmax) row = rowmax;
        const u16* gp = g + (size_t)row * ld + k0 + kg * 8;
        async_cp16(gp, lds + (size_t)(j * 256 + w * 64) * 8);
    }
}

// 128x128 block, 4 waves (2x2 of 64x64), one BK=32 step
__device__ __forceinline__ void compute_step(const u16* shA, const u16* shB,
                                             int wm, int wn, int lane,
                                             f32x4 acc[4][4])
{
    const int lr = lane & 15, lk = (lane >> 4) * 8;
    bf16x8 a[4], b[4];
    #pragma unroll
    for (int i = 0; i < 4; ++i)
        a[i] = *(const bf16x8*)(shA + (size_t)(wm * 64 + i * 16 + lr) * 32 + lk);
    #pragma unroll
    for (int j = 0; j < 4; ++j)
        b[j] = *(const bf16x8*)(shB + (size_t)(wn * 64 + j * 16 + lr) * 32 + lk);
    #pragma unroll
    for (int i = 0; i < 4; ++i)
        #pragma unroll
        for (int j = 0; j < 4; ++j)
            acc[i][j] = __builtin_amdgcn_mfma_f32_16x16x32_bf16(a[i], b[j], acc[i][j], 0, 0, 0);
}

// =====================================================================
// merged converts: blocks [0,4380) = x->xb cast; [4380,7452) = w^T cast
// =====================================================================
#define CVT_BLKS  4380   // M1*DIM/4/256
#define CVTW_BLKS 3072   // (N3/32)*(DIM/32)
__global__ void k_cvt_all(const float* __restrict__ x, const float* __restrict__ w,
                          u16* __restrict__ xb, u16* __restrict__ wb)
{
    __shared__ float tile[32][33];
    const int bid = blockIdx.x;
    if (bid < CVT_BLKS) {
        int i = bid * 256 + threadIdx.x;
        f32x4 f = *(const f32x4*)(x + (size_t)i * 4);
        u16x4 o;
        #pragma unroll
        for (int k = 0; k < 4; ++k) o[k] = f2b(f[k]);
        *(u16x4*)(xb + (size_t)i * 4) = o;
    } else {
        const int b2 = bid - CVT_BLKS;
        const int n0 = (b2 % (N3 / 32)) * 32, k0 = (b2 / (N3 / 32)) * 32;
        const int tx = threadIdx.x & 31, ty = threadIdx.x >> 5;   // ty 0..7
        #pragma unroll
        for (int r = 0; r < 32; r += 8)
            tile[ty + r][tx] = w[(size_t)(k0 + ty + r) * N3 + n0 + tx];
        __syncthreads();
        #pragma unroll
        for (int r = 0; r < 32; r += 8)
            wb[(size_t)(n0 + ty + r) * DIM + k0 + tx] = f2b(tile[tx][ty + r]);
    }
}

// =====================================================================
// qkv GEMM: xb[8760][512] @ wb^T -> scatter q/k/v (bf16)  [round-8]
// =====================================================================
__global__ void k_qkv(const u16* __restrict__ xb, const u16* __restrict__ wb,
                      u16* __restrict__ qws, u16* __restrict__ kws,
                      u16* __restrict__ vws)
{
    __shared__ u16 sh[2][2][4096];
    const int t = threadIdx.x, lane = t & 63, w = t >> 6;
    const int wm = w >> 1, wn = w & 1;
    const int m0 = blockIdx.y * 128, n0 = blockIdx.x * 128;
    f32x4 acc[4][4] = {};

    stage128x32(xb, DIM, m0, M1 - 1, 0, sh[0][0]);
    stage128x32(wb, DIM, n0, N3 - 1, 0, sh[0][1]);
    const int nt = DIM / 32;   // 16
    for (int kt = 0; kt < nt; ++kt) {
        int cur = kt & 1;
        __syncthreads();
        if (kt + 1 < nt) {
            stage128x32(xb, DIM, m0, M1 - 1, (kt + 1) * 32, sh[cur ^ 1][0]);
            stage128x32(wb, DIM, n0, N3 - 1, (kt + 1) * 32, sh[cur ^ 1][1]);
        }
        compute_step(sh[cur][0], sh[cur][1], wm, wn, lane, acc);
    }

    const int lr = lane & 15, lq = lane >> 4;
    #pragma unroll
    for (int i = 0; i < 4; ++i) {
        #pragma unroll
        for (int j = 0; j < 4; ++j) {
            #pragma unroll
            for (int q = 0; q < 4; ++q) {
                int m = m0 + wm * 64 + i * 16 + lq * 4 + q;
                if (m >= M1) continue;
                int col = n0 + wn * 64 + j * 16 + lr;
                int b = m / NSEQ, n = m - b * NSEQ;
                int part = col >> 11, within = col & 2047;
                int h = within >> 8, d = within & 255;
                int bh = b * HEADS + h;
                float val = acc[i][j][q];
                size_t idx = ((size_t)bh * NSEQ + n) * DHEAD + d;
                if (part == 0)      qws[idx] = f2b(val * SCALE_F);
                else if (part == 1) kws[idx] = f2b(val);
                else                vws[idx] = f2b(val);
            }
        }
    }
}

// =====================================================================
// transpose v: vws[bh][n][d] -> vtp (n<284, padded) and vth (n>=284)
// =====================================================================
__global__ void k_vT(const u16* __restrict__ vws, u16* __restrict__ vtp,
                     u16* __restrict__ vth)
{
    __shared__ u16 tile[64][72];
    const int bh = blockIdx.z;
    const int n0 = blockIdx.x * 64, d0 = blockIdx.y * 64;
    const int t = threadIdx.x;

    #pragma unroll
    for (int i = 0; i < 16; ++i) {
        int lin = i * 256 + t;
        int r = lin >> 6, c = lin & 63;
        int n = n0 + r;
        tile[r][c] = (n < NSEQ) ? vws[((size_t)bh * NSEQ + n) * DHEAD + d0 + c] : (u16)0;
    }
    __syncthreads();

    #pragma unroll
    for (int i = 0; i < 16; ++i) {
        int lin = i * 256 + t;
        int r2 = lin >> 6, c2 = lin & 63;
        int n = n0 + c2, d = d0 + r2;
        u16 v = tile[c2][r2];
        if (n < NPATH) {
            vtp[((size_t)bh * DHEAD + d) * VTPLD + n] = v;
        } else {
            if (n < NPATH + 4)
                vtp[((size_t)bh * DHEAD + d) * VTPLD + n] = 0;
            if (n < NSEQ)
                vth[((size_t)bh * DHEAD + d) * VTHLD + (n - NPATH)] = v;
        }
    }
}

// =====================================================================
// merged scores: blocks [0,1680) = kp (q@k_p^T -> out1/out3);
//                blocks [1680,3216) = kh (q_p@k_h^T -> out2)
// =====================================================================
#define KP_BLKS 1680   // 3 * 35 * 16
#define KH_BLKS 1536   // 32 * 3 * 16
__global__ void k_scores_all(const u16* __restrict__ qws, const u16* __restrict__ kws,
                             float* __restrict__ out1, float* __restrict__ out2,
                             float* __restrict__ out3)
{
    __shared__ u16 sh[2][2][4096];
    const int t = threadIdx.x, lane = t & 63, w = t >> 6;
    const int wm = w >> 1, wn = w & 1;
    const int lr = lane & 15, lq = lane >> 4;
    const int bid = blockIdx.x;

    if (bid < KP_BLKS) {
        const int jx = bid % 3, iy = (bid / 3) % 35, bh = bid / 105;
        const int i0 = iy * 128, j0 = jx * 128;
        const u16* A = qws + (size_t)bh * NSEQ * DHEAD;
        const u16* B = kws + (size_t)bh * NSEQ * DHEAD;
        f32x4 acc[4][4] = {};

        stage128x32(A, DHEAD, i0, NSEQ - 1, 0, sh[0][0]);
        stage128x32(B, DHEAD, j0, NSEQ - 1, 0, sh[0][1]);
        for (int kt = 0; kt < 8; ++kt) {
            int cur = kt & 1;
            __syncthreads();
            if (kt + 1 < 8) {
                stage128x32(A, DHEAD, i0, NSEQ - 1, (kt + 1) * 32, sh[cur ^ 1][0]);
                stage128x32(B, DHEAD, j0, NSEQ - 1, (kt + 1) * 32, sh[cur ^ 1][1]);
            }
            compute_step(sh[cur][0], sh[cur][1], wm, wn, lane, acc);
        }

        #pragma unroll
        for (int i = 0; i < 4; ++i) {
            #pragma unroll
            for (int j = 0; j < 4; ++j) {
                #pragma unroll
                for (int q = 0; q < 4; ++q) {
                    int ig = i0 + wm * 64 + i * 16 + lq * 4 + q;
                    int jg = j0 + wn * 64 + j * 16 + lr;
                    if (ig >= NSEQ || jg >= NPATH) continue;
                    float val = acc[i][j][q];
                    if (ig < NPATH)
                        out1[((size_t)bh * NPATH + ig) * NPATH + jg] = val;
                    else
                        out3[((size_t)bh * NHIST + (ig - NPATH)) * NPATH + jg] = val;
                }
            }
        }
    } else {
        const int b2 = bid - KP_BLKS;
        const int jx = b2 % 32, iy = (b2 / 32) % 3, bh = b2 / 96;
        const int i0 = iy * 128, j0 = jx * 128;
        const u16* A = qws + (size_t)bh * NSEQ * DHEAD;
        const u16* B = kws + ((size_t)bh * NSEQ + NPATH) * DHEAD;
        f32x4 acc[4][4] = {};

        stage128x32(A, DHEAD, i0, NSEQ - 1, 0, sh[0][0]);
        stage128x32(B, DHEAD, j0, NHIST - 1, 0, sh[0][1]);
        for (int kt = 0; kt < 8; ++kt) {
            int cur = kt & 1;
            __syncthreads();
            if (kt + 1 < 8) {
                stage128x32(A, DHEAD, i0, NSEQ - 1, (kt + 1) * 32, sh[cur ^ 1][0]);
                stage128x32(B, DHEAD, j0, NHIST - 1, (kt + 1) * 32, sh[cur ^ 1][1]);
            }
            compute_step(sh[cur][0], sh[cur][1], wm, wn, lane, acc);
        }

        #pragma unroll
        for (int i = 0; i < 4; ++i) {
            #pragma unroll
            for (int j = 0; j < 4; ++j) {
                #pragma unroll
                for (int q = 0; q < 4; ++q) {
                    int ig = i0 + wm * 64 + i * 16 + lq * 4 + q;
                    if (ig >= NPATH) continue;
                    int jg = j0 + wn * 64 + j * 16 + lr;
                    out2[((size_t)bh * NPATH + ig) * NHIST + jg] = acc[i][j][q];
                }
            }
        }
    }
}

// =====================================================================
// merged softmax: blocks [0,4544) = sm2 rows; [4544,20928) = sm3 (4 rows/blk)
// =====================================================================
#define SM2_BLKS 4544
#define SM3_BLKS 16384
__global__ void k_sm_all(const float* __restrict__ sc2, const float* __restrict__ sc3,
                         u16* __restrict__ p2, u16* __restrict__ p3)
{
    __shared__ float buf[NHIST];     // 16 KB (sm2 branch only)
    __shared__ float red[4];
    __shared__ float bc[2];
    const int bid = blockIdx.x;
    const int tid = threadIdx.x;

    if (bid < SM2_BLKS) {
        const int row = bid;
        const float* p = sc2 + (size_t)row * NHIST;

        #pragma unroll
        for (int k = 0; k < 4; ++k) {
            int j4 = tid + k * 256;
            ((f32x4*)buf)[j4] = ((const f32x4*)p)[j4];
        }
        __syncthreads();

        float m = -1e30f;
        #pragma unroll
        for (int k = 0; k < 16; ++k) m = fmaxf(m, buf[tid + k * 256]);
        #pragma unroll
        for (int o = 32; o >= 1; o >>= 1) m = fmaxf(m, __shfl_xor(m, o));
        if ((tid & 63) == 0) red[tid >> 6] = m;
        __syncthreads();
        m = fmaxf(fmaxf(red[0], red[1]), fmaxf(red[2], red[3]));

        float s = 0.f;
        #pragma unroll
        for (int k = 0; k < 16; ++k) {
            int j = tid + k * 256;
            float e = __expf(buf[j] - m);
            buf[j] = e;
            s += e;
        }
        #pragma unroll
        for (int o = 32; o >= 1; o >>= 1) s += __shfl_xor(s, o);
        __syncthreads();
        if ((tid & 63) == 0) red[tid >> 6] = s;
        __syncthreads();
        if (tid == 0) bc[0] = 1.f / (red[0] + red[1] + red[2] + red[3]);
        __syncthreads();
        const float inv = bc[0];

        u16* pr = p2 + (size_t)row * NHIST;
        #pragma unroll
        for (int k = 0; k < 4; ++k) {
            int j4 = tid + k * 256;
            f32x4 f = ((const f32x4*)buf)[j4];
            u16x4 o;
            #pragma unroll
            for (int e = 0; e < 4; ++e) o[e] = f2b(f[e] * inv);
            *(u16x4*)(pr + (size_t)j4 * 4) = o;
        }
    } else {
        const int row  = (bid - SM2_BLKS) * 4 + (tid >> 6);
        const int lane = tid & 63;
        const float* p = sc3 + (size_t)row * NPATH;

        float v[5];
        #pragma unroll
        for (int k = 0; k < 5; ++k) {
            int j = lane + k * 64;
            v[k] = (j < NPATH) ? p[j] : -1e30f;
        }

        float m = fmaxf(fmaxf(fmaxf(v[0], v[1]), fmaxf(v[2], v[3])), v[4]);
        #pragma unroll
        for (int o = 32; o >= 1; o >>= 1) m = fmaxf(m, __shfl_xor(m, o));

        float s = 0.f;
        #pragma unroll
        for (int k = 0; k < 5; ++k) {
            float e = __expf(v[k] - m);
            v[k] = e;
            s += e;
        }
        #pragma unroll
        for (int o = 32; o >= 1; o >>= 1) s += __shfl_xor(s, o);
        const float inv = 1.f / s;

        u16* pr = p3 + (size_t)row * P3LD;
        #pragma unroll
        for (int k = 0; k < 5; ++k) {
            int j = lane + k * 64;
            if (j < P3LD)
                pr[j] = (j < NPATH) ? f2b(v[k] * inv) : (u16)0;
        }
    }
}

// =====================================================================
// merged PV: blocks [0,384) = path split-K partials; [384,1408) = hist
// =====================================================================
#define PVP_BLKS 384    // 2 * 3 * 64
#define PVH_BLKS 1024   // 2 * 32 * 16
__global__ void k_pv_all(const u16* __restrict__ p2, const u16* __restrict__ vth,
                         const u16* __restrict__ p3, const u16* __restrict__ vtp,
                         float* __restrict__ pp, float* __restrict__ out0)
{
    __shared__ u16 sh[2][2][4096];
    const int t = threadIdx.x, lane = t & 63, w = t >> 6;
    const int wm = w >> 1, wn = w & 1;
    const int lr = lane & 15, lq = lane >> 4;
    const int bid = blockIdx.x;

    if (bid < PVP_BLKS) {
        const int dx = bid % 2, iy = (bid / 2) % 3, z = bid / 6;
        const int bh = z >> 2, ks = z & 3;
        const int i0 = iy * 128, d0 = dx * 128;
        const int kb = ks * 1024;
        const u16* A = p2 + (size_t)bh * NPATH * NHIST;
        const u16* B = vth + (size_t)bh * DHEAD * VTHLD;
        f32x4 acc[4][4] = {};

        stage128x32(A, NHIST, i0, NPATH - 1, kb, sh[0][0]);
        stage128x32(B, VTHLD, d0, DHEAD - 1, kb, sh[0][1]);
        for (int kt = 0; kt < 32; ++kt) {
            int cur = kt & 1;
            __syncthreads();
            if (kt + 1 < 32) {
                stage128x32(A, NHIST, i0, NPATH - 1, kb + (kt + 1) * 32, sh[cur ^ 1][0]);
                stage128x32(B, VTHLD, d0, DHEAD - 1, kb + (kt + 1) * 32, sh[cur ^ 1][1]);
            }
            compute_step(sh[cur][0], sh[cur][1], wm, wn, lane, acc);
        }

        float* pb = pp + ((size_t)ks * NBH + bh) * 384 * 256;
        #pragma unroll
        for (int i = 0; i < 4; ++i) {
            #pragma unroll
            for (int j = 0; j < 4; ++j) {
                #pragma unroll
                for (int q = 0; q < 4; ++q) {
                    int mrow = i0 + wm * 64 + i * 16 + lq * 4 + q;
                    int d = d0 + wn * 64 + j * 16 + lr;
                    pb[(size_t)mrow * 256 + d] = acc[i][j][q];
                }
            }
        }
    } else {
        const int b2 = bid - PVP_BLKS;
        const int dx = b2 % 2, iy = (b2 / 2) % 32, bh = b2 / 64;
        const int b = bh >> 3, h = bh & 7;
        const int i0 = iy * 128, d0 = dx * 128;
        const u16* A = p3 + (size_t)bh * NHIST * P3LD;
        const u16* B = vtp + (size_t)bh * DHEAD * VTPLD;
        f32x4 acc[4][4] = {};

        stage128x32(A, P3LD, i0, NHIST - 1, 0, sh[0][0]);
        stage128x32(B, VTPLD, d0, DHEAD - 1, 0, sh[0][1]);
        for (int kt = 0; kt < 9; ++kt) {
            int cur = kt & 1;
            __syncthreads();
            if (kt + 1 < 9) {
                stage128x32(A, P3LD, i0, NHIST - 1, (kt + 1) * 32, sh[cur ^ 1][0]);
                stage128x32(B, VTPLD, d0, DHEAD - 1, (kt + 1) * 32, sh[cur ^ 1][1]);
            }
            compute_step(sh[cur][0], sh[cur][1], wm, wn, lane, acc);
        }

        #pragma unroll
        for (int i = 0; i < 4; ++i) {
            #pragma unroll
            for (int j = 0; j < 4; ++j) {
                #pragma unroll
                for (int q = 0; q < 4; ++q) {
                    int mrow = i0 + wm * 64 + i * 16 + lq * 4 + q;
                    int d = d0 + wn * 64 + j * 16 + lr;
                    out0[((size_t)(b * NSEQ + NPATH + mrow)) * INNER + h * DHEAD + d] = acc[i][j][q];
                }
            }
        }
    }
}

// reduce 4 partials -> out0 rows 0..283 (fixed order: deterministic)
__global__ void k_pv_reduce(const float* __restrict__ pp, float* __restrict__ out0)
{
    const int i = blockIdx.x;            // 0..283
    const int bh = blockIdx.y;
    const int d = threadIdx.x;
    const int b = bh >> 3, h = bh & 7;
    const size_t kstr = (size_t)NBH * 384 * 256;
    size_t base = ((size_t)bh * 384 + i) * 256 + d;
    float s = pp[base] + pp[base + kstr] + pp[base + 2 * kstr] + pp[base + 3 * kstr];
    out0[((size_t)(b * NSEQ + i)) * INNER + h * DHEAD + d] = s;
}

// =====================================================================
// depthwise conv over seq, accumulate into out0
// =====================================================================
__global__ void k_conv3(const u16* __restrict__ vws, const float* __restrict__ wconv,
                        float* __restrict__ out0)
{
    __shared__ u16 lv[64][DHEAD];        // 32 KB bf16
    const int bh = blockIdx.z, b = bh >> 3, h = bh & 7;
    const int n0 = blockIdx.y * 32;
    const int t = threadIdx.x;
    const u16* vb = vws + (size_t)bh * NSEQ * DHEAD;

    #pragma unroll
    for (int i = 0; i < 8; ++i) {
        int oct = i * 256 + t;
        int r = oct >> 5, o = oct & 31;
        int n = n0 - 16 + r;
        bf16x8 v = {};
        if (n >= 0 && n < NSEQ)
            v = *(const bf16x8*)(vb + (size_t)n * DHEAD + o * 8);
        *(bf16x8*)(&lv[r][o * 8]) = v;
    }
    __syncthreads();

    float wc[KSZ];
    #pragma unroll
    for (int tt = 0; tt < KSZ; ++tt) wc[tt] = wconv[h * KSZ + tt];

    const int d = t;
    float win[KSZ];
    #pragma unroll
    for (int j = 0; j < KSZ; ++j) win[j] = b2f(lv[j][d]);

    float* op = out0 + ((size_t)(b * NSEQ + n0)) * INNER + h * DHEAD + d;
    #pragma unroll
    for (int i = 0; i < 32; ++i) {
        if (n0 + i < NSEQ) {
            float acc = 0.f;
            #pragma unroll
            for (int tt = 0; tt < KSZ; ++tt)
                acc += win[(i + tt) % KSZ] * wc[tt];
            op[(size_t)i * INNER] += acc;
        }
        if (i < 31)
            win[i % KSZ] = b2f(lv[i + KSZ][d]);
    }
}

// =====================================================================
extern "C" void kernel_launch(void* const* d_in, const int* in_sizes, int n_in,
                              void* d_out, int out_size, void* d_ws, size_t ws_size,
                              hipStream_t stream)
{
    const float* x     = (const float*)d_in[0];
    const float* wqkv  = (const float*)d_in[1];
    const float* wconv = (const float*)d_in[2];
    float* out = (float*)d_out;
    char*  ws  = (char*)d_ws;

    u16* xb  = (u16*)(ws + XB_OFF);
    u16* wb  = (u16*)(ws + WB_OFF);
    u16* qws = (u16*)(ws + QW_OFF);
    u16* kws = (u16*)(ws + KW_OFF);
    u16* vws = (u16*)(ws + VW_OFF);
    u16* vth = (u16*)(ws + VTH_OFF);
    u16* vtp = (u16*)(ws + VTP_OFF);
    u16* p2  = (u16*)(ws + P2_OFF);
    u16* p3  = (u16*)(ws + P3_OFF);
    float* pp = (float*)(ws + PP_OFF);

    float* out0 = out + OUT0_OFF;
    float* out1 = out + OUT1_OFF;
    float* out2 = out + OUT2_OFF;
    float* out3 = out + OUT3_OFF;

    dim3 blk(256);

    // 1. converts (merged)
    k_cvt_all<<<dim3(CVT_BLKS + CVTW_BLKS), blk, 0, stream>>>(x, wqkv, xb, wb);

    // 2. qkv GEMM
    k_qkv<<<dim3(N3 / 128, (M1 + 127) / 128), blk, 0, stream>>>(xb, wb, qws, kws, vws);

    // 3. v transpose
    k_vT<<<dim3((NSEQ + 63) / 64, DHEAD / 64, NBH), blk, 0, stream>>>(vws, vtp, vth);

    // 4. scores (merged kp + kh)
    k_scores_all<<<dim3(KP_BLKS + KH_BLKS), blk, 0, stream>>>(qws, kws, out1, out2, out3);

    // 5. softmax (merged sm2 + sm3)
    k_sm_all<<<dim3(SM2_BLKS + SM3_BLKS), blk, 0, stream>>>(out2, out3, p2, p3);

    // 6. PV (merged path-split + hist)
    k_pv_all<<<dim3(PVP_BLKS + PVH_BLKS), blk, 0, stream>>>(p2, vth, p3, vtp, pp, out0);

    // 7. path reduce
    k_pv_reduce<<<dim3(NPATH, NBH), blk, 0, stream>>>(pp, out0);

    // 8. conv accumulate
    k_conv3<<<dim3(1, (NSEQ + 31) / 32, NBH), blk, 0, stream>>>(vws, wconv, out0);
}